// Round 1
// 526.462 us; speedup vs baseline: 1.1639x; 1.1639x over previous
//
#include <hip/hip_runtime.h>
#include <math.h>

#define CDIM 256
#define LDIM 16384
#define NH 8
#define HD 32
#define FFN 512
#define EPS 1e-5f
#define SCALE 0.17677669529663687f  // 1/sqrt(32)

#define RB 64               // rows per block
#define NCHUNK 256          // LDIM/RB
#define LDA 264             // padded bf16 leading dim
#define PSTRIDE 258         // 256 m~ cols + M + S

typedef __attribute__((ext_vector_type(8))) short short8;
typedef __attribute__((ext_vector_type(4))) float f32x4;

union U8 { short8 s8; unsigned u[4]; };

// f32 -> bf16 (round-to-nearest-even)
__device__ inline unsigned short f2bf(float x) {
    unsigned int u = __float_as_uint(x);
    unsigned int lsb = (u >> 16) & 1u;
    u += 0x7fffu + lsb;
    return (unsigned short)(u >> 16);
}

// ---------------- kernel 0: convert Wip to bf16 fragment layout ----------------
// w1[((t*16 + c)*64 + l)*8 + j] = bf16(Wip[t*32 + (l>>4)*8 + j][c*16 + (l&15)])

__global__ __launch_bounds__(256) void convert_weights(const float* __restrict__ Wip,
                                                       unsigned short* __restrict__ w1) {
    int idx = blockIdx.x * 256 + threadIdx.x;   // 65536 threads
    int j = idx & 7, l = (idx >> 3) & 63, c = (idx >> 9) & 15, t = idx >> 13;
    int k = t * 32 + (l >> 4) * 8 + j;
    int colc = c * 16 + (l & 15);
    w1[idx] = f2bf(Wip[k * CDIM + colc]);
}

// ---------------- kernel 1: q-prep: qs = (ln(query)@Wq + bq)*scale, then
//   w~[k][h] = sum_d Wkv[k][h*32+d]*qs[h*32+d]  (bf16, fragment layout, heads 8..15 = 0)
//   qc[h]    = sum_d bkv[h*32+d]*qs[h*32+d]

__global__ __launch_bounds__(256) void qprep_kernel(const float* __restrict__ query,
                                                    const float* __restrict__ Wq,
                                                    const float* __restrict__ bq,
                                                    const float* __restrict__ gq,
                                                    const float* __restrict__ beq,
                                                    const float* __restrict__ Wkv,
                                                    const float* __restrict__ bkv,
                                                    float* __restrict__ qs,
                                                    unsigned short* __restrict__ wts,
                                                    float* __restrict__ qcb) {
    int b = blockIdx.x;
    int tid = threadIdx.x;
    int wave = tid >> 6, lane = tid & 63;
    __shared__ float sh[CDIM];
    __shared__ float qsh[CDIM];
    __shared__ float red[8];

    float x = query[b * CDIM + tid];
    float s = x, sq = x * x;
#pragma unroll
    for (int m = 32; m >= 1; m >>= 1) { s += __shfl_xor(s, m, 64); sq += __shfl_xor(sq, m, 64); }
    if (lane == 0) { red[wave] = s; red[4 + wave] = sq; }
    __syncthreads();
    float ts = red[0] + red[1] + red[2] + red[3];
    float tq = red[4] + red[5] + red[6] + red[7];
    float mean = ts * (1.f / CDIM);
    float var = tq * (1.f / CDIM) - mean * mean;
    float rstd = rsqrtf(var + EPS);
    sh[tid] = (x - mean) * rstd * gq[tid] + beq[tid];
    __syncthreads();

    float acc = bq[tid];
    for (int k = 0; k < CDIM; ++k) acc = fmaf(sh[k], Wq[k * CDIM + tid], acc);
    float qv = acc * SCALE;
    qs[b * CDIM + tid] = qv;
    qsh[tid] = qv;
    __syncthreads();

    // w~ : thread owns row k = tid
    float wa[8];
#pragma unroll
    for (int h = 0; h < 8; ++h) wa[h] = 0.f;
    const float* wr = Wkv + (size_t)tid * (2 * CDIM);
#pragma unroll
    for (int h = 0; h < 8; ++h)
#pragma unroll
        for (int d = 0; d < 32; ++d)
            wa[h] = fmaf(wr[h * 32 + d], qsh[h * 32 + d], wa[h]);
    // fragment layout: element (t,l,j): t = k>>5, l = ((k>>3)&3)*16 + h, j = k&7
    unsigned short* wb = wts + (b << 12) + ((tid >> 5) << 9) + (((tid >> 3) & 3) << 7) + (tid & 7);
#pragma unroll
    for (int h = 0; h < 8; ++h) wb[h << 3] = f2bf(wa[h]);
#pragma unroll
    for (int h = 8; h < 16; ++h) wb[h << 3] = 0;

    if (tid < 16) {
        float cb = 0.f;
        if (tid < 8) {
#pragma unroll
            for (int d = 0; d < 32; ++d) cb = fmaf(bkv[tid * 32 + d], qsh[tid * 32 + d], cb);
        }
        qcb[b * 16 + tid] = cb;
    }
}

// ---------------- MFMA tile GEMM: 64x(64 per wave) from LDS-A x swizzled-global-B ----------------

__device__ inline void mfma_gemm(const unsigned short* __restrict__ smA,
                                 const unsigned short* __restrict__ wsw, int NC, int ctile0,
                                 int lx, int quad, f32x4 acc[4][4]) {
#pragma unroll
    for (int rt = 0; rt < 4; ++rt)
#pragma unroll
        for (int ci = 0; ci < 4; ++ci) acc[rt][ci] = (f32x4){0.f, 0.f, 0.f, 0.f};

    int l = quad * 16 + lx;
#pragma unroll
    for (int t = 0; t < 8; ++t) {
        short8 bfrag[4];
#pragma unroll
        for (int ci = 0; ci < 4; ++ci)
            bfrag[ci] = *(const short8*)(wsw + (((size_t)(t * NC + ctile0 + ci)) * 64 + l) * 8);
        short8 afrag[4];
#pragma unroll
        for (int rt = 0; rt < 4; ++rt)
            afrag[rt] = *(const short8*)(smA + (rt * 16 + lx) * LDA + t * 32 + quad * 8);
#pragma unroll
        for (int rt = 0; rt < 4; ++rt)
#pragma unroll
            for (int ci = 0; ci < 4; ++ci)
                acc[rt][ci] = __builtin_amdgcn_mfma_f32_16x16x32_bf16(afrag[rt], bfrag[ci], acc[rt][ci], 0, 0, 0);
    }
}

// S = M @ w~ : single 16-wide col-tile (cols = heads, 8..15 zero)

__device__ inline void mfma_svec(const unsigned short* __restrict__ smA,
                                 const unsigned short* __restrict__ wt,
                                 int lx, int quad, f32x4 accS[4]) {
#pragma unroll
    for (int rt = 0; rt < 4; ++rt) accS[rt] = (f32x4){0.f, 0.f, 0.f, 0.f};
    int l = quad * 16 + lx;
#pragma unroll
    for (int t = 0; t < 8; ++t) {
        short8 bf = *(const short8*)(wt + ((t * 64 + l) << 3));
        short8 af[4];
#pragma unroll
        for (int rt = 0; rt < 4; ++rt)
            af[rt] = *(const short8*)(smA + (rt * 16 + lx) * LDA + t * 32 + quad * 8);
#pragma unroll
        for (int rt = 0; rt < 4; ++rt)
            accS[rt] = __builtin_amdgcn_mfma_f32_16x16x32_bf16(af[rt], bf, accS[rt], 0, 0, 0);
    }
}

// ---------------- kernel 2: fused mem pipeline + per-chunk attention partials ----------------
// One GEMM (Wip) + 16-wide score MFMA + Pt@M MFMA. Writes per (b,chunk,h):
// m~[256] (unnormalized exp-weighted sum of M rows), chunk max M, chunk denom S.

__global__ __launch_bounds__(256, 4) void main_kernel(const float* __restrict__ mem,
                                                      const unsigned short* __restrict__ w1,
                                                      const unsigned short* __restrict__ wts,
                                                      const float* __restrict__ bip,
                                                      const float* __restrict__ gip,
                                                      const float* __restrict__ beip,
                                                      const float* __restrict__ qcb,
                                                      const float* __restrict__ ior,
                                                      float* __restrict__ partials) {
    int blk = blockIdx.x;
    int b = blk >> 8;
    int chunk = blk & 255;
    int row0 = chunk * RB;
    int tid = threadIdx.x;
    int w = tid >> 6, lane = tid & 63;
    int quad = lane >> 4, lx = lane & 15;

    __shared__ unsigned short bufA[RB * LDA];      // 33 KiB: mem bf16, then M bf16
    __shared__ float iorS[NH][66];                 // padded for bank spread on [h][row] reads
    __shared__ float redS[4][RB];
    __shared__ float redQ[4][RB];
    __shared__ float stats[2][RB];

    // stage ior chunk (8 heads x 64 rows)
    {
        int i0 = tid, i1 = tid + 256;
        iorS[i0 >> 6][i0 & 63] = ior[((size_t)(b * NH + (i0 >> 6))) * LDIM + row0 + (i0 & 63)];
        iorS[i1 >> 6][i1 & 63] = ior[((size_t)(b * NH + (i1 >> 6))) * LDIM + row0 + (i1 & 63)];
    }
    // stage mem rows -> bufA bf16 (coalesced float4 reads)
    {
        const float4* src = (const float4*)(mem + ((size_t)b * LDIM + row0) * CDIM);
#pragma unroll
        for (int it = 0; it < 16; ++it) {
            int i = tid + 256 * it;
            int r = i >> 6, c4 = i & 63;
            float4 v = src[i];
            ushort4 u;
            u.x = f2bf(v.x); u.y = f2bf(v.y); u.z = f2bf(v.z); u.w = f2bf(v.w);
            *(ushort4*)&bufA[r * LDA + c4 * 4] = u;
        }
    }
    __syncthreads();

    int col[4];
#pragma unroll
    for (int ci = 0; ci < 4; ++ci) col[ci] = (4 * w + ci) * 16 + lx;

    // ---- GEMM1: relu(mem @ Wip + bip) ----
    f32x4 acc[4][4];
    mfma_gemm(bufA, w1, 16, 4 * w, lx, quad, acc);

    float bb[4], gg[4], ee[4];
#pragma unroll
    for (int ci = 0; ci < 4; ++ci) { bb[ci] = bip[col[ci]]; gg[ci] = gip[col[ci]]; ee[ci] = beip[col[ci]]; }

    // bias+relu in-place, per-row LN stats (wave-partial over 64 of 256 cols)
#pragma unroll
    for (int rt = 0; rt < 4; ++rt) {
#pragma unroll
        for (int reg = 0; reg < 4; ++reg) {
#pragma unroll
            for (int ci = 0; ci < 4; ++ci)
                acc[rt][ci][reg] = fmaxf(acc[rt][ci][reg] + bb[ci], 0.f);
            float s2 = acc[rt][0][reg] + acc[rt][1][reg] + acc[rt][2][reg] + acc[rt][3][reg];
            float q2 = acc[rt][0][reg] * acc[rt][0][reg] + acc[rt][1][reg] * acc[rt][1][reg]
                     + acc[rt][2][reg] * acc[rt][2][reg] + acc[rt][3][reg] * acc[rt][3][reg];
#pragma unroll
            for (int m = 8; m >= 1; m >>= 1) { s2 += __shfl_xor(s2, m, 64); q2 += __shfl_xor(q2, m, 64); }
            if (lx == 0) {
                int row = rt * 16 + quad * 4 + reg;
                redS[w][row] = s2;
                redQ[w][row] = q2;
            }
        }
    }
    __syncthreads();   // also guarantees all GEMM1 reads of bufA are done
    if (tid < RB) {
        float s2 = redS[0][tid] + redS[1][tid] + redS[2][tid] + redS[3][tid];
        float q2 = redQ[0][tid] + redQ[1][tid] + redQ[2][tid] + redQ[3][tid];
        float mean = s2 * (1.f / CDIM);
        float var = q2 * (1.f / CDIM) - mean * mean;
        stats[0][tid] = mean;
        stats[1][tid] = rsqrtf(var + EPS);
    }
    __syncthreads();

    // LN -> bf16 M into bufA, plus packed-bf16 copy in registers for the PV B-fragments.
    // ypk0[rt][ci] = rows (rt*16+quad*4+{0,1}), ypk1 = rows {2,3}, at col[ci].
    unsigned ypk0[4][4], ypk1[4][4];
#pragma unroll
    for (int rt = 0; rt < 4; ++rt) {
        float mn[4], rs[4];
#pragma unroll
        for (int reg = 0; reg < 4; ++reg) {
            int row = rt * 16 + quad * 4 + reg;
            mn[reg] = stats[0][row];
            rs[reg] = stats[1][row];
        }
#pragma unroll
        for (int ci = 0; ci < 4; ++ci) {
            unsigned short u0 = f2bf((acc[rt][ci][0] - mn[0]) * rs[0] * gg[ci] + ee[ci]);
            unsigned short u1 = f2bf((acc[rt][ci][1] - mn[1]) * rs[1] * gg[ci] + ee[ci]);
            unsigned short u2 = f2bf((acc[rt][ci][2] - mn[2]) * rs[2] * gg[ci] + ee[ci]);
            unsigned short u3 = f2bf((acc[rt][ci][3] - mn[3]) * rs[3] * gg[ci] + ee[ci]);
            int rbase = rt * 16 + quad * 4;
            bufA[(rbase + 0) * LDA + col[ci]] = u0;
            bufA[(rbase + 1) * LDA + col[ci]] = u1;
            bufA[(rbase + 2) * LDA + col[ci]] = u2;
            bufA[(rbase + 3) * LDA + col[ci]] = u3;
            ypk0[rt][ci] = (unsigned)u0 | ((unsigned)u1 << 16);
            ypk1[rt][ci] = (unsigned)u2 | ((unsigned)u3 << 16);
        }
    }
    __syncthreads();

    // ---- scores: S = M @ w~ ; col = head (lane&15), row = rt*16+quad*4+reg ----
    f32x4 accS[4];
    mfma_svec(bufA, wts + ((size_t)b << 12), lx, quad, accS);

    float qcv = qcb[(b << 4) + lx];   // 0 for lx>=8
    float p[16];
    float cmax = -1e30f;
#pragma unroll
    for (int rt = 0; rt < 4; ++rt)
#pragma unroll
        for (int reg = 0; reg < 4; ++reg) {
            int row = rt * 16 + quad * 4 + reg;
            float sc = (accS[rt][reg] + qcv) * iorS[lx & 7][row];
            p[rt * 4 + reg] = sc;
            cmax = fmaxf(cmax, sc);
        }
    cmax = fmaxf(cmax, __shfl_xor(cmax, 16, 64));
    cmax = fmaxf(cmax, __shfl_xor(cmax, 32, 64));
    float csum = 0.f;
#pragma unroll
    for (int i = 0; i < 16; ++i) { p[i] = __expf(p[i] - cmax); csum += p[i]; }
    csum += __shfl_xor(csum, 16, 64);
    csum += __shfl_xor(csum, 32, 64);

    // ---- PV: m~(16x256) = P^T(16x64) @ M(64x256), fragments via cross-lane shuffles ----
    f32x4 accPV[4];
#pragma unroll
    for (int ci = 0; ci < 4; ++ci) accPV[ci] = (f32x4){0.f, 0.f, 0.f, 0.f};

    int srcA = ((quad & 1) << 5) + lx;   // source quad (quad&1)*2, same lx
    int srcB = srcA + 16;                // next quad
    bool hiQ = quad >= 2;                // selects rt' = t2*2+1 slice
#pragma unroll
    for (int t2 = 0; t2 < 2; ++t2) {
        // A-fragment: pa[j] = p_{head=lx}[row = t2*32 + quad*8 + j]
        float pe[8];
#pragma unroll
        for (int jj = 0; jj < 4; ++jj) {
            float v0 = __shfl(p[t2 * 8 + jj], srcA, 64);
            float v1 = __shfl(p[t2 * 8 + 4 + jj], srcA, 64);
            pe[jj] = hiQ ? v1 : v0;
            float v2 = __shfl(p[t2 * 8 + jj], srcB, 64);
            float v3 = __shfl(p[t2 * 8 + 4 + jj], srcB, 64);
            pe[4 + jj] = hiQ ? v3 : v2;
        }
        U8 pa;
        pa.u[0] = (unsigned)f2bf(pe[0]) | ((unsigned)f2bf(pe[1]) << 16);
        pa.u[1] = (unsigned)f2bf(pe[2]) | ((unsigned)f2bf(pe[3]) << 16);
        pa.u[2] = (unsigned)f2bf(pe[4]) | ((unsigned)f2bf(pe[5]) << 16);
        pa.u[3] = (unsigned)f2bf(pe[6]) | ((unsigned)f2bf(pe[7]) << 16);

#pragma unroll
        for (int ci = 0; ci < 4; ++ci) {
            // B-fragment: bu[j] = M[row = t2*32 + quad*8 + j][col[ci]]
            unsigned a0 = (unsigned)__shfl((int)ypk0[t2 * 2][ci], srcA, 64);
            unsigned b0 = (unsigned)__shfl((int)ypk0[t2 * 2 + 1][ci], srcA, 64);
            unsigned a1 = (unsigned)__shfl((int)ypk1[t2 * 2][ci], srcA, 64);
            unsigned b1 = (unsigned)__shfl((int)ypk1[t2 * 2 + 1][ci], srcA, 64);
            unsigned a2 = (unsigned)__shfl((int)ypk0[t2 * 2][ci], srcB, 64);
            unsigned b2 = (unsigned)__shfl((int)ypk0[t2 * 2 + 1][ci], srcB, 64);
            unsigned a3 = (unsigned)__shfl((int)ypk1[t2 * 2][ci], srcB, 64);
            unsigned b3 = (unsigned)__shfl((int)ypk1[t2 * 2 + 1][ci], srcB, 64);
            U8 ub;
            ub.u[0] = hiQ ? b0 : a0;
            ub.u[1] = hiQ ? b1 : a1;
            ub.u[2] = hiQ ? b2 : a2;
            ub.u[3] = hiQ ? b3 : a3;
            accPV[ci] = __builtin_amdgcn_mfma_f32_16x16x32_bf16(pa.s8, ub.s8, accPV[ci], 0, 0, 0);
        }
    }

    // ---- write partials: m~ rows 0..7 are heads; rows 8..15 discarded ----
    size_t pb = ((size_t)(b * NCHUNK + chunk)) * NH * PSTRIDE;
    if (quad < 2) {
#pragma unroll
        for (int reg = 0; reg < 4; ++reg) {
            float* dst = partials + pb + (size_t)(quad * 4 + reg) * PSTRIDE;
#pragma unroll
            for (int ci = 0; ci < 4; ++ci) dst[col[ci]] = accPV[ci][reg];
        }
    }
    if (quad == 0 && lx < 8) {
        float* dst = partials + pb + (size_t)lx * PSTRIDE;
        dst[256] = cmax;
        dst[257] = csum;
    }
}

// ---------------- kernel 3: flash-merge partials + V projection ----------------
// out_h = (sum_c wf_c * m~_c) / (sum_c wf_c * S_c) @ Wv[:,hcols] + bv_h

__global__ __launch_bounds__(256) void combine_kernel(const float* __restrict__ partials,
                                                      const float* __restrict__ Wkv,
                                                      const float* __restrict__ bkv,
                                                      float* __restrict__ attnout) {
    int bh = blockIdx.x;
    int b = bh >> 3, h = bh & 7;
    int tid = threadIdx.x;
    __shared__ float ms[NCHUNK], wf[NCHUNK], mt[CDIM];
    __shared__ float sredA[4];
    __shared__ float ored[8][33];

    const float* base = partials + ((size_t)b * NCHUNK * NH + h) * PSTRIDE;
    ms[tid] = base[(size_t)tid * NH * PSTRIDE + 256];
    __syncthreads();
    float M = -1e30f;
    for (int s = 0; s < NCHUNK; ++s) M = fmaxf(M, ms[s]);
    float e = __expf(ms[tid] - M);
    wf[tid] = e;
    float Sl = base[(size_t)tid * NH * PSTRIDE + 257] * e;
#pragma unroll
    for (int m = 32; m >= 1; m >>= 1) Sl += __shfl_xor(Sl, m, 64);
    if ((tid & 63) == 0) sredA[tid >> 6] = Sl;
    __syncthreads();
    float St = sredA[0] + sredA[1] + sredA[2] + sredA[3];

    float acc = 0.f;
    for (int s = 0; s < NCHUNK; ++s) acc = fmaf(wf[s], base[(size_t)s * NH * PSTRIDE + tid], acc);
    mt[tid] = acc / St;
    __syncthreads();

    int d = tid & 31, g = tid >> 5;
    float a2 = 0.f;
    for (int c = g * 32; c < g * 32 + 32; ++c)
        a2 = fmaf(mt[c], Wkv[(size_t)c * (2 * CDIM) + CDIM + h * 32 + d], a2);
    ored[g][d] = a2;
    __syncthreads();
    if (tid < 32) {
        float o = bkv[CDIM + h * 32 + tid];
#pragma unroll
        for (int gg2 = 0; gg2 < 8; ++gg2) o += ored[gg2][tid];
        attnout[b * CDIM + h * HD + tid] = o;
    }
}

// ---------------- kernel 4: x = attn+query; y = x + FFN(ln(x)) ----------------

__global__ __launch_bounds__(256) void epilogue_kernel(const float* __restrict__ attnout,
                                                       const float* __restrict__ query,
                                                       const float* __restrict__ gf,
                                                       const float* __restrict__ bef,
                                                       const float* __restrict__ W1,
                                                       const float* __restrict__ b1,
                                                       const float* __restrict__ W2,
                                                       const float* __restrict__ b2,
                                                       float* __restrict__ out) {
    int b = blockIdx.x;
    int tid = threadIdx.x;
    int wave = tid >> 6, lane = tid & 63;
    __shared__ float sh[FFN];
    __shared__ float red[8];

    float x = attnout[b * CDIM + tid] + query[b * CDIM + tid];
    float s = x, sq = x * x;
#pragma unroll
    for (int m = 32; m >= 1; m >>= 1) { s += __shfl_xor(s, m, 64); sq += __shfl_xor(sq, m, 64); }
    if (lane == 0) { red[wave] = s; red[4 + wave] = sq; }
    __syncthreads();
    float ts = red[0] + red[1] + red[2] + red[3];
    float tq = red[4] + red[5] + red[6] + red[7];
    float mean = ts * (1.f / CDIM);
    float var = tq * (1.f / CDIM) - mean * mean;
    float rstd = rsqrtf(var + EPS);
    sh[tid] = (x - mean) * rstd * gf[tid] + bef[tid];
    __syncthreads();

    float t[2];
#pragma unroll
    for (int i = 0; i < 2; ++i) {
        int f = tid + 256 * i;
        float a = b1[f];
        for (int k = 0; k < CDIM; ++k) a = fmaf(sh[k], W1[k * FFN + f], a);
        t[i] = 0.5f * a * (1.f + erff(a * 0.7071067811865476f));
    }
    __syncthreads();
    sh[tid] = t[0];
    sh[tid + 256] = t[1];
    __syncthreads();

    float y = b2[tid];
    for (int f = 0; f < FFN; ++f) y = fmaf(sh[f], W2[f * CDIM + tid], y);
    out[b * CDIM + tid] = x + y;
}

// ---------------- launch ----------------

extern "C" void kernel_launch(void* const* d_in, const int* in_sizes, int n_in,
                              void* d_out, int out_size, void* d_ws, size_t ws_size,
                              hipStream_t stream) {
    const float* query = (const float*)d_in[0];
    const float* mem   = (const float*)d_in[1];
    const float* ior   = (const float*)d_in[2];
    const float* Wip   = (const float*)d_in[3];
    const float* bip   = (const float*)d_in[4];
    const float* gip   = (const float*)d_in[5];
    const float* beip  = (const float*)d_in[6];
    const float* Wq    = (const float*)d_in[7];
    const float* bq    = (const float*)d_in[8];
    const float* Wkv   = (const float*)d_in[9];
    const float* bkv   = (const float*)d_in[10];
    const float* gq    = (const float*)d_in[11];
    const float* beq   = (const float*)d_in[12];
    const float* gf    = (const float*)d_in[13];
    const float* bef   = (const float*)d_in[14];
    const float* W1    = (const float*)d_in[15];
    const float* b1    = (const float*)d_in[16];
    const float* W2    = (const float*)d_in[17];
    const float* b2    = (const float*)d_in[18];
    float* out = (float*)d_out;

    char* ws = (char*)d_ws;
    float* qs             = (float*)(ws);                    // 16384 B
    float* attnout        = (float*)(ws + 16384);            // 16384 B
    float* qcb            = (float*)(ws + 32768);            // 1024 B
    unsigned short* w1sw  = (unsigned short*)(ws + 33792);   // 131072 B
    unsigned short* wtsw  = (unsigned short*)(ws + 164864);  // 131072 B
    float* partials       = (float*)(ws + 295936);           // 16*256*8*258*4 = 33816576 B

    const int B = 16;

    convert_weights<<<256, 256, 0, stream>>>(Wip, w1sw);
    qprep_kernel<<<B, 256, 0, stream>>>(query, Wq, bq, gq, beq, Wkv, bkv, qs, wtsw, qcb);
    main_kernel<<<B * NCHUNK, 256, 0, stream>>>(mem, w1sw, wtsw, bip, gip, beip, qcb, ior, partials);
    combine_kernel<<<B * NH, 256, 0, stream>>>(partials, Wkv, bkv, attnout);
    epilogue_kernel<<<B, 256, 0, stream>>>(attnout, query, gf, bef, W1, b1, W2, b2, out);
}